// Round 1
// 629.454 us; speedup vs baseline: 1.1624x; 1.1624x over previous
//
#include <hip/hip_runtime.h>

// GraphPooling: voxel-grid pooling.
//  inputs: x[N,64] f32, pos[N,3] f32, edge_index[E,2] i32, batch[N] i32
//  outputs (concat, f32): pooled_x[M,64], pos_mean[M,3], ei_out[Ed+M,2], new_batch[M]
// Keyspace: key = ((b*s0+qx)*s1+qy)*s2+qz < 16*32*32*32 = 524288.
// Edge pipeline: partition by src>>9 (1024 partitions, ~5.8k edges each),
// per-partition LDS counting-sort by srcLow + element-parallel rank-sort by dst,
// global (in-partition) dedup flag + block scan compaction.
// Codes packed as (src<<19)|dst (38 bits); in-LDS code28 = (srcLow<<19)|dst.

#define KSP 524288
#define SCAN_BLOCK 256
#define SCAN_ITEMS 16
#define SCAN_CHUNK 4096            // SCAN_BLOCK * SCAN_ITEMS
#define NCHUNK (KSP / SCAN_CHUNK)  // 128
#define NPART 1024
#define PB 512                     // voxel ranks per partition (KSP/NPART)
#define SCAP2 8192                 // LDS cap: edges per partition (mean ~5.8k, sigma ~150)

// ws header slots (u32): [0..2]=max qpos, [3]=M, [4]=validE, [5]=Ed

__device__ __forceinline__ unsigned encF(float f) {
  unsigned u = __float_as_uint(f);
  return (u & 0x80000000u) ? ~u : (u | 0x80000000u);
}
__device__ __forceinline__ float decF(unsigned u) {
  return (u & 0x80000000u) ? __uint_as_float(u & 0x7FFFFFFFu)
                           : __uint_as_float(~u);
}

// ---- per-point: max of quantized coords ----
__global__ void k_qmax(const float* __restrict__ pos, unsigned* hdr, int N) {
  __shared__ unsigned sm[3];
  if (threadIdx.x < 3) sm[threadIdx.x] = 0;
  __syncthreads();
  int i = blockIdx.x * blockDim.x + threadIdx.x;
  if (i < N) {
    int q0 = (int)floorf(pos[3 * i + 0] * 0.25f);
    int q1 = (int)floorf(pos[3 * i + 1] * 0.25f);
    int q2 = (int)floorf(pos[3 * i + 2] * 0.25f);
    atomicMax(&sm[0], (unsigned)q0);
    atomicMax(&sm[1], (unsigned)q1);
    atomicMax(&sm[2], (unsigned)q2);
  }
  __syncthreads();
  if (threadIdx.x < 3) atomicMax(&hdr[threadIdx.x], sm[threadIdx.x]);
}

// ---- per-point: voxel key + histogram ----
__global__ void k_keys(const float* __restrict__ pos, const int* __restrict__ batch,
                       const unsigned* __restrict__ hdr, unsigned* __restrict__ key,
                       unsigned* __restrict__ cnt, int N) {
  int i = blockIdx.x * blockDim.x + threadIdx.x;
  if (i >= N) return;
  unsigned s0 = hdr[0] + 1, s1 = hdr[1] + 1, s2 = hdr[2] + 1;
  unsigned q0 = (unsigned)(int)floorf(pos[3 * i + 0] * 0.25f);
  unsigned q1 = (unsigned)(int)floorf(pos[3 * i + 1] * 0.25f);
  unsigned q2 = (unsigned)(int)floorf(pos[3 * i + 2] * 0.25f);
  unsigned k = (((unsigned)batch[i] * s0 + q0) * s1 + q1) * s2 + q2;
  key[i] = k;
  atomicAdd(&cnt[k], 1u);
}

// ---- 3-phase exclusive scan over KSP ----
__global__ void scanA(const unsigned* __restrict__ in, unsigned* __restrict__ out,
                      unsigned* __restrict__ chunkSums, int n, int presence) {
  __shared__ unsigned lds[SCAN_BLOCK];
  int tbase = blockIdx.x * SCAN_CHUNK + threadIdx.x * SCAN_ITEMS;
  unsigned vals[SCAN_ITEMS];
  unsigned sum = 0;
  for (int i = 0; i < SCAN_ITEMS; ++i) {
    unsigned v = 0;
    int idx = tbase + i;
    if (idx < n) { v = in[idx]; if (presence) v = v ? 1u : 0u; }
    vals[i] = sum;
    sum += v;
  }
  lds[threadIdx.x] = sum;
  __syncthreads();
  for (int off = 1; off < SCAN_BLOCK; off <<= 1) {
    unsigned t = (threadIdx.x >= (unsigned)off) ? lds[threadIdx.x - off] : 0u;
    __syncthreads();
    lds[threadIdx.x] += t;
    __syncthreads();
  }
  unsigned threadExcl = lds[threadIdx.x] - sum;
  for (int i = 0; i < SCAN_ITEMS; ++i) {
    int idx = tbase + i;
    if (idx < n) out[idx] = threadExcl + vals[i];
  }
  if (threadIdx.x == SCAN_BLOCK - 1) chunkSums[blockIdx.x] = lds[SCAN_BLOCK - 1];
}

__global__ void scanB(unsigned* chunkSums, unsigned* totalDst, int nchunks) {
  __shared__ unsigned lds[1024];
  unsigned v = (threadIdx.x < (unsigned)nchunks) ? chunkSums[threadIdx.x] : 0u;
  lds[threadIdx.x] = v;
  __syncthreads();
  for (int off = 1; off < 1024; off <<= 1) {
    unsigned t = (threadIdx.x >= (unsigned)off) ? lds[threadIdx.x - off] : 0u;
    __syncthreads();
    lds[threadIdx.x] += t;
    __syncthreads();
  }
  if (threadIdx.x < (unsigned)nchunks) chunkSums[threadIdx.x] = lds[threadIdx.x] - v;
  if (threadIdx.x == 0 && totalDst) *totalDst = lds[1023];
}

__global__ void scanC(unsigned* __restrict__ out, unsigned* __restrict__ out2,
                      const unsigned* __restrict__ chunkSums, int n) {
  int idx = blockIdx.x * blockDim.x + threadIdx.x;
  if (idx >= n) return;
  unsigned v = out[idx] + chunkSums[idx / SCAN_CHUNK];
  out[idx] = v;
  if (out2) out2[idx] = v;
}

// ---- single-block exclusive scan of NPART entries ----
__global__ void k_scan1024(const unsigned* __restrict__ in, unsigned* __restrict__ outStart,
                           unsigned* __restrict__ outCursor, unsigned* __restrict__ totalDst) {
  __shared__ unsigned lds[NPART];
  unsigned t = threadIdx.x;
  unsigned v = in[t];
  lds[t] = v;
  __syncthreads();
  for (int off = 1; off < NPART; off <<= 1) {
    unsigned x = (t >= (unsigned)off) ? lds[t - off] : 0u;
    __syncthreads();
    lds[t] += x;
    __syncthreads();
  }
  unsigned excl = lds[t] - v;
  outStart[t] = excl;
  if (outCursor) outCursor[t] = excl;
  if (t == NPART - 1) {
    outStart[NPART] = lds[t];
    if (totalDst) *totalDst = lds[t];
  }
}

// ---- build rank -> key map ----
__global__ void k_ukey(const unsigned* __restrict__ cnt, const unsigned* __restrict__ rank,
                       unsigned* __restrict__ ukeyArr) {
  int k = blockIdx.x * blockDim.x + threadIdx.x;
  if (k >= KSP) return;
  if (cnt[k]) ukeyArr[rank[k]] = (unsigned)k;
}

// ---- per-point: inv index + pos accumulation ----
__global__ void k_inv_pos(const unsigned* __restrict__ key, const unsigned* __restrict__ rank,
                          unsigned* __restrict__ inv, const float* __restrict__ pos,
                          float* __restrict__ out, const unsigned* __restrict__ hdr, int N) {
  int i = blockIdx.x * blockDim.x + threadIdx.x;
  if (i >= N) return;
  unsigned m = rank[key[i]];
  inv[i] = m;
  unsigned M = hdr[3];
  unsigned long long O1 = 64ull * M;
  atomicAdd(&out[O1 + 3ull * m + 0], pos[3 * i + 0]);
  atomicAdd(&out[O1 + 3ull * m + 1], pos[3 * i + 1]);
  atomicAdd(&out[O1 + 3ull * m + 2], pos[3 * i + 2]);
}

// ---- per-(point,feature): encoded atomic max ----
__global__ void k_xmax(const float* __restrict__ x, const unsigned* __restrict__ inv,
                       float* __restrict__ out, long long total) {
  long long t = (long long)blockIdx.x * blockDim.x + threadIdx.x;
  if (t >= total) return;
  int i = (int)(t >> 6);
  int d = (int)(t & 63);
  unsigned m = inv[i];
  unsigned e = encF(x[t]);
  atomicMax((unsigned*)&out[(unsigned long long)m * 64u + d], e);
}

__global__ void k_decode(float* __restrict__ out, const unsigned* __restrict__ hdr) {
  long long idx = (long long)blockIdx.x * blockDim.x + threadIdx.x;
  unsigned M = hdr[3];
  if (idx >= (long long)M * 64) return;
  unsigned u = __float_as_uint(out[idx]);
  out[idx] = decF(u);
}

__global__ void k_posdiv(float* __restrict__ out, const unsigned* __restrict__ hdr,
                         const unsigned* __restrict__ ukeyArr, const unsigned* __restrict__ cnt) {
  int m = blockIdx.x * blockDim.x + threadIdx.x;
  unsigned M = hdr[3];
  if ((unsigned)m >= M) return;
  float c = (float)cnt[ukeyArr[m]];
  unsigned long long O1 = 64ull * M;
  out[O1 + 3ull * m + 0] /= c;
  out[O1 + 3ull * m + 1] /= c;
  out[O1 + 3ull * m + 2] /= c;
}

// ---- edges: partition histogram (LDS-aggregated) ----
__global__ void __launch_bounds__(256) k_ehist2(const int2* __restrict__ ei,
                                                const unsigned* __restrict__ inv,
                                                unsigned* __restrict__ partCnt, int E, int span) {
  __shared__ unsigned h[NPART];
  for (int i = threadIdx.x; i < NPART; i += 256) h[i] = 0;
  __syncthreads();
  int lo = blockIdx.x * span;
  int hi = min(E, lo + span);
  for (int e = lo + threadIdx.x; e < hi; e += 256) {
    int2 pr = ei[e];
    unsigned a = inv[pr.x], b = inv[pr.y];
    if (a != b) atomicAdd(&h[a >> 9], 1u);
  }
  __syncthreads();
  for (int i = threadIdx.x; i < NPART; i += 256) {
    unsigned v = h[i];
    if (v) atomicAdd(&partCnt[i], v);
  }
}

// ---- edges: partition scatter (block-reserved contiguous runs) ----
__global__ void __launch_bounds__(256) k_pscatter(const int2* __restrict__ ei,
                                                  const unsigned* __restrict__ inv,
                                                  unsigned* __restrict__ partCursor,
                                                  unsigned long long* __restrict__ pStage,
                                                  int E, int span) {
  __shared__ unsigned h[NPART];
  for (int i = threadIdx.x; i < NPART; i += 256) h[i] = 0;
  __syncthreads();
  int lo = blockIdx.x * span;
  int hi = min(E, lo + span);
  for (int e = lo + threadIdx.x; e < hi; e += 256) {
    int2 pr = ei[e];
    unsigned a = inv[pr.x], b = inv[pr.y];
    if (a != b) atomicAdd(&h[a >> 9], 1u);
  }
  __syncthreads();
  for (int i = threadIdx.x; i < NPART; i += 256) {
    unsigned v = h[i];
    h[i] = v ? atomicAdd(&partCursor[i], v) : 0u;
  }
  __syncthreads();
  for (int e = lo + threadIdx.x; e < hi; e += 256) {
    int2 pr = ei[e];
    unsigned a = inv[pr.x], b = inv[pr.y];
    if (a != b) {
      unsigned off = atomicAdd(&h[a >> 9], 1u);
      pStage[off] = ((unsigned long long)a << 19) | b;
    }
  }
}

// ---- per-partition: LDS counting-sort by srcLow, element-parallel rank-sort by dst,
//      global dedup flag + block-scan compaction ----
// code28 = (srcLow<<19)|dst; full 38-bit code = ((u64)p<<28)|code28.
__global__ void __launch_bounds__(256) k_bucket(unsigned long long* __restrict__ pStage,
                                                const unsigned* __restrict__ partStart,
                                                unsigned* __restrict__ partDistinct) {
  __shared__ unsigned dstL[SCAP2];
  __shared__ unsigned h[PB];
  __shared__ unsigned bbase[PB + 1];
  __shared__ unsigned stmp[256];
  unsigned p = blockIdx.x;
  unsigned s = partStart[p];
  unsigned c = partStart[p + 1] - s;
  unsigned t = threadIdx.x;
  for (int i = t; i < PB; i += 256) h[i] = 0;
  __syncthreads();
  if (c <= SCAP2) {
    // low dword of each 8B code holds all 28 relevant bits (little-endian)
    const unsigned* lo32 = (const unsigned*)(pStage + s);
    // 1) histogram by srcLow
    for (unsigned i = t; i < c; i += 256) {
      unsigned code28 = lo32[2 * i] & 0x0FFFFFFFu;
      atomicAdd(&h[code28 >> 19], 1u);
    }
    __syncthreads();
    {  // 2) exclusive scan h -> bbase
      unsigned a = h[2 * t], b = h[2 * t + 1], sum = a + b;
      stmp[t] = sum;
      __syncthreads();
      for (int off = 1; off < 256; off <<= 1) {
        unsigned x = (t >= (unsigned)off) ? stmp[t - off] : 0u;
        __syncthreads(); stmp[t] += x; __syncthreads();
      }
      unsigned excl = stmp[t] - sum;
      bbase[2 * t] = excl; bbase[2 * t + 1] = excl + a;
      if (t == 255) bbase[PB] = stmp[255];
    }
    __syncthreads();
    for (int i = t; i < PB; i += 256) h[i] = bbase[i];  // h becomes cursor
    __syncthreads();
    // 3) scatter code28 into bucket-contiguous LDS
    for (unsigned i = t; i < c; i += 256) {
      unsigned code28 = lo32[2 * i] & 0x0FFFFFFFu;
      unsigned off = atomicAdd(&h[code28 >> 19], 1u);
      dstL[off] = code28;
    }
    __syncthreads();
    // 4) element-parallel stable rank within bucket (independent, pipelined LDS reads)
    unsigned L = (c + 255) >> 8;  // elements per thread (blocked), <= 32
    unsigned vv[32], rr[32];
#pragma unroll
    for (unsigned k = 0; k < 32; ++k) {
      unsigned i = t * L + k;
      if (k < L && i < c) {
        unsigned v = dstL[i];
        unsigned b = v >> 19;
        unsigned blo = bbase[b], bhi = bbase[b + 1];
        unsigned r = blo;
        for (unsigned j = blo; j < bhi; ++j) {
          unsigned u = dstL[j];
          r += (u < v) || (u == v && j < i);
        }
        vv[k] = v; rr[k] = r;
      }
    }
    __syncthreads();
    // 5) in-place scatter to sorted position
#pragma unroll
    for (unsigned k = 0; k < 32; ++k) {
      unsigned i = t * L + k;
      if (k < L && i < c) dstL[rr[k]] = vv[k];
    }
    __syncthreads();
    // 6) dedup flags (whole partition is now sorted by code28) + block scan
    unsigned flm = 0, localSum = 0;
#pragma unroll
    for (unsigned k = 0; k < 32; ++k) {
      unsigned i = t * L + k;
      if (k < L && i < c) {
        unsigned v = dstL[i];
        unsigned pv = dstL[i - (i > 0 ? 1u : 0u)];
        unsigned f = (i == 0) | (pv != v);
        flm |= f << k;
        localSum += f;
      }
    }
    stmp[t] = localSum;
    __syncthreads();
    for (int off = 1; off < 256; off <<= 1) {
      unsigned x = (t >= (unsigned)off) ? stmp[t - off] : 0u;
      __syncthreads(); stmp[t] += x; __syncthreads();
    }
    unsigned pos = stmp[t] - localSum;
    unsigned long long pbase = (unsigned long long)p << 28;
    // 7) compact distinct codes back to pStage (sorted by (src,dst))
#pragma unroll
    for (unsigned k = 0; k < 32; ++k) {
      unsigned i = t * L + k;
      if (k < L && i < c && ((flm >> k) & 1u)) {
        pStage[s + pos] = pbase | (unsigned long long)dstL[i];
        ++pos;
      }
    }
    if (t == 255) partDistinct[p] = stmp[255];
  } else if (t == 0) {  // fallback, statistically unreachable (mean+24sigma)
    for (unsigned i = 1; i < c; ++i) {
      unsigned long long v = pStage[s + i];
      long long j = (long long)i - 1;
      while (j >= 0 && pStage[s + j] > v) { pStage[s + j + 1] = pStage[s + j]; --j; }
      pStage[s + j + 1] = v;
    }
    unsigned d = 0;
    unsigned long long prev = ~0ull;
    for (unsigned i = 0; i < c; ++i) {
      unsigned long long v = pStage[s + i];
      if (i == 0 || v != prev) { pStage[s + d] = v; ++d; }
      prev = v;
    }
    partDistinct[p] = d;
  }
}

// ---- write deduped edges ----
__global__ void __launch_bounds__(256) k_ewriteP(const unsigned long long* __restrict__ pStage,
                                                 const unsigned* __restrict__ partStart,
                                                 const unsigned* __restrict__ partOut,
                                                 const unsigned* __restrict__ hdr,
                                                 float* __restrict__ out) {
  unsigned p = blockIdx.x;
  unsigned s = partStart[p];
  unsigned rbase = partOut[p];
  unsigned d = partOut[p + 1] - rbase;
  unsigned M = hdr[3];
  unsigned long long O2 = 67ull * M;
  for (unsigned j = threadIdx.x; j < d; j += 256) {
    unsigned long long code = pStage[s + j];
    unsigned long long row = (unsigned long long)rbase + j;
    out[O2 + 2 * row + 0] = (float)(unsigned)(code >> 19);
    out[O2 + 2 * row + 1] = (float)(unsigned)(code & 0x7FFFFu);
  }
}

// ---- self loops + new_batch ----
__global__ void k_final(const unsigned* __restrict__ ukeyArr, const unsigned* __restrict__ hdr,
                        float* __restrict__ out) {
  unsigned m = blockIdx.x * blockDim.x + threadIdx.x;
  unsigned M = hdr[3];
  if (m >= M) return;
  unsigned Ed = hdr[5];
  unsigned long long O2 = 67ull * M;
  unsigned long long row = (unsigned long long)Ed + m;
  float fm = (float)m;
  out[O2 + 2 * row + 0] = fm;
  out[O2 + 2 * row + 1] = fm;
  unsigned s0 = hdr[0] + 1, s1 = hdr[1] + 1, s2 = hdr[2] + 1;
  unsigned vol = s0 * s1 * s2;
  unsigned long long O3 = O2 + 2ull * (Ed + M);
  out[O3 + m] = (float)(ukeyArr[m] / vol);
}

extern "C" void kernel_launch(void* const* d_in, const int* in_sizes, int n_in,
                              void* d_out, int out_size, void* d_ws, size_t ws_size,
                              hipStream_t stream) {
  const float* x = (const float*)d_in[0];
  const float* pos = (const float*)d_in[1];
  const int* ei = (const int*)d_in[2];
  const int* batch = (const int*)d_in[3];
  float* out = (float*)d_out;
  int N = in_sizes[3];
  int E = in_sizes[2] / 2;

  unsigned* ws = (unsigned*)d_ws;
  // ws layout (u32 units)
  unsigned* hdr          = ws;                        // 64
  unsigned* cnt          = ws + 64;                   // KSP
  unsigned* partCnt      = cnt + KSP;                 // NPART
  unsigned* partDistinct = partCnt + NPART;           // NPART
  unsigned* rank         = partDistinct + NPART;      // KSP
  unsigned* ukeyArr      = rank + KSP;                // KSP
  unsigned* partStart    = ukeyArr + KSP;             // NPART+2
  unsigned* partCursor   = partStart + NPART + 2;     // NPART
  unsigned* partOut      = partCursor + NPART;        // NPART+2
  unsigned* chunkSums    = partOut + NPART + 2;       // 1024
  unsigned* key          = chunkSums + 1024;          // N
  unsigned* inv          = key + N;                   // N
  unsigned* pS32         = inv + ((N + 1) & ~1);      // 8B-aligned
  unsigned long long* pStage = (unsigned long long*)pS32;  // E u64

  // zero: hdr + cnt + partCnt + partDistinct (contiguous); all of d_out
  hipMemsetAsync(ws, 0, (size_t)(64 + KSP + 2 * NPART) * 4, stream);
  hipMemsetAsync(d_out, 0, (size_t)out_size * 4, stream);

  const int B = 256;
  int gN = (N + B - 1) / B;
  int gK = (KSP + B - 1) / B;
  long long totalX = (long long)N * 64;
  int gX = (int)((totalX + B - 1) / B);
  int gD = (int)(((long long)KSP * 64 + B - 1) / B);
  int span = (E + 255) / 256;  // edges per block for the 256-block edge passes

  k_qmax<<<gN, B, 0, stream>>>(pos, hdr, N);
  k_keys<<<gN, B, 0, stream>>>(pos, batch, hdr, key, cnt, N);

  // rank = exclusive scan of presence(cnt); total -> hdr[3] = M
  scanA<<<NCHUNK, SCAN_BLOCK, 0, stream>>>(cnt, rank, chunkSums, KSP, 1);
  scanB<<<1, 1024, 0, stream>>>(chunkSums, &hdr[3], NCHUNK);
  scanC<<<gK, B, 0, stream>>>(rank, nullptr, chunkSums, KSP);

  k_ukey<<<gK, B, 0, stream>>>(cnt, rank, ukeyArr);
  k_inv_pos<<<gN, B, 0, stream>>>(key, rank, inv, pos, out, hdr, N);
  k_xmax<<<gX, B, 0, stream>>>(x, inv, out, totalX);
  k_decode<<<gD, B, 0, stream>>>(out, hdr);
  k_posdiv<<<gK, B, 0, stream>>>(out, hdr, ukeyArr, cnt);

  // edges: partition -> LDS sort/dedup -> write
  const int2* ei2 = (const int2*)ei;
  k_ehist2<<<256, 256, 0, stream>>>(ei2, inv, partCnt, E, span);
  k_scan1024<<<1, NPART, 0, stream>>>(partCnt, partStart, partCursor, &hdr[4]);
  k_pscatter<<<256, 256, 0, stream>>>(ei2, inv, partCursor, pStage, E, span);
  k_bucket<<<NPART, 256, 0, stream>>>(pStage, partStart, partDistinct);
  k_scan1024<<<1, NPART, 0, stream>>>(partDistinct, partOut, nullptr, &hdr[5]);
  k_ewriteP<<<NPART, 256, 0, stream>>>(pStage, partStart, partOut, hdr, out);
  k_final<<<gK, B, 0, stream>>>(ukeyArr, hdr, out);

  (void)n_in; (void)ws_size;
}